// Round 1
// baseline (127.441 us; speedup 1.0000x reference)
//
#include <hip/hip_runtime.h>

#define W 512
#define NPIX (512*512)

// ---------------- reduction: min/max of y ----------------
__global__ __launch_bounds__(256) void k_reduce(const float* __restrict__ y,
                                                float* __restrict__ partial) {
    __shared__ float smn[256], smx[256];
    int t = threadIdx.x;
    int base = blockIdx.x * 1024 + t;
    float mn = 1e30f, mx = -1e30f;
#pragma unroll
    for (int k = 0; k < 4; ++k) {
        float v = y[base + k * 256];
        mn = fminf(mn, v);
        mx = fmaxf(mx, v);
    }
    smn[t] = mn; smx[t] = mx;
    __syncthreads();
    for (int off = 128; off > 0; off >>= 1) {
        if (t < off) {
            smn[t] = fminf(smn[t], smn[t + off]);
            smx[t] = fmaxf(smx[t], smx[t + off]);
        }
        __syncthreads();
    }
    if (t == 0) {
        partial[blockIdx.x]       = smn[0];
        partial[256 + blockIdx.x] = smx[0];
    }
}

__global__ __launch_bounds__(256) void k_sigma(const float* __restrict__ partial,
                                               const float* __restrict__ r,
                                               float* __restrict__ invout) {
    __shared__ float smn[256], smx[256];
    int t = threadIdx.x;
    smn[t] = partial[t];
    smx[t] = partial[256 + t];
    __syncthreads();
    for (int off = 128; off > 0; off >>= 1) {
        if (t < off) {
            smn[t] = fminf(smn[t], smn[t + off]);
            smx[t] = fmaxf(smx[t], smx[t + off]);
        }
        __syncthreads();
    }
    if (t == 0) {
        float sigma = r[0] * (smx[0] - smn[0]);
        float hh = 0.5f * sigma;
        invout[0] = 1.0f / (hh * hh);   // 1/((sigma/2)^2)
    }
}

// ---------------- 9x9 box filter (zero-padded, /81) ----------------
__global__ __launch_bounds__(256) void k_base(const float* __restrict__ X,
                                              const float* __restrict__ y,
                                              float* __restrict__ Xb,
                                              float* __restrict__ yb) {
    int c = blockIdx.x * 64 + threadIdx.x;
    int h = blockIdx.y * 4 + threadIdx.y;
    float sx = 0.f, sy = 0.f;
#pragma unroll
    for (int dy = -4; dy <= 4; ++dy) {
        int nh = h + dy;
        if ((unsigned)nh < 512u) {
            const float* xr = X + nh * W;
            const float* yr = y + nh * W;
#pragma unroll
            for (int dx = -4; dx <= 4; ++dx) {
                int nc = c + dx;
                if ((unsigned)nc < 512u) {
                    sx += xr[nc];
                    sy += yr[nc];
                }
            }
        }
    }
    const float inv81 = 1.0f / 81.0f;
    Xb[h * W + c] = sx * inv81;
    yb[h * W + c] = sy * inv81;
}

// ---------------- main fused kernel ----------------
__global__ __launch_bounds__(256) void k_main(const float* __restrict__ X,
                                              const float* __restrict__ y,
                                              const float* __restrict__ Xb,
                                              const float* __restrict__ yb,
                                              const float* __restrict__ invp,
                                              float* __restrict__ out) {
    __shared__ float sb[361];   // 19x19 spatial kernel
    __shared__ float sd[45];    // 5x9 spatial kernel
    int t = threadIdx.y * 64 + threadIdx.x;
    for (int i = t; i < 361; i += 256) {
        int dy = i / 19 - 9, dx = i % 19 - 9;
        sb[i] = __expf(-(float)(dy * dy + dx * dx) / 8145.0625f);  // (19*19/4)^2
    }
    if (t < 45) {
        int dy = t / 9 - 2, dx = t % 9 - 4;
        sd[t] = __expf(-(float)(dy * dy + dx * dx) / 126.5625f);   // (5*9/4)^2
    }
    __syncthreads();

    float inv_s2 = invp[0];
    int c = blockIdx.x * 64 + threadIdx.x;
    int h = blockIdx.y * 4 + threadIdx.y;

    // chunk mapping: output col -> owning chunk after overlap-trim
    int chunk = (c == 0) ? 0 : (c - 1) / 62;
    if (chunk > 8) chunk = 8;
    int s = 62 * chunk;
    int e = (chunk == 8) ? 512 : (s + 64);

    // ---- base pass: 19x19 bilateral guided-filter stats ----
    float Xc = Xb[h * W + c];
    float sw = 0.f, swy = 0.f, swx = 0.f, swxx = 0.f, swxy = 0.f;
    for (int dy = -9; dy <= 9; ++dy) {
        int nh = h + dy;
        bool vh = (unsigned)nh < 512u;
        int rr = vh ? nh : h;
        const float* xrow = Xb + rr * W;
        const float* yrow = yb + rr * W;
        const float* sbr = sb + (dy + 9) * 19;
#pragma unroll
        for (int dx = -9; dx <= 9; ++dx) {
            int nc = c + dx;
            bool vc = (nc >= s) & (nc < e);
            int cc = vc ? nc : c;   // clamped in-bounds load, weight zeroed below
            float xv = xrow[cc];
            float yv = yrow[cc];
            float d = xv - Xc;
            float w = __expf(-d * d * inv_s2) * sbr[dx + 9];
            w = (vh & vc) ? w : 0.f;
            sw += w;
            swx  = fmaf(w, xv, swx);
            swy  = fmaf(w, yv, swy);
            swxx = fmaf(w * xv, xv, swxx);
            swxy = fmaf(w * xv, yv, swxy);
        }
    }

    // ---- detail pass: 5(h)x9(w) bilateral on residuals ----
    float xcen = X[h * W + c];
    float Xdc = xcen - Xc;
    float swd = 0.f, sv = 0.f;
    for (int dy = -2; dy <= 2; ++dy) {
        int nh = h + dy;
        bool vh = (unsigned)nh < 512u;
        int rr = vh ? nh : h;
        const float* Xrow = X + rr * W;
        const float* Yrow = y + rr * W;
        const float* xbrow = Xb + rr * W;
        const float* ybrow = yb + rr * W;
        const float* sdr = sd + (dy + 2) * 9;
#pragma unroll
        for (int dx = -4; dx <= 4; ++dx) {
            int nc = c + dx;
            bool vc = (nc >= s) & (nc < e);
            int cc = vc ? nc : c;
            float xd = Xrow[cc] - xbrow[cc];
            float yd = Yrow[cc] - ybrow[cc];
            float dd = xd - Xdc;
            float w = __expf(-dd * dd * inv_s2) * sdr[dx + 4];
            w = (vh & vc) ? w : 0.f;
            swd += w;
            sv = fmaf(w, yd - xd, sv);
        }
    }

    // ---- combine ----
    float inv_sw = 1.0f / sw;
    float mx = swx * inv_sw, my = swy * inv_sw;
    float varx = fmaf(-mx, mx, swxx * inv_sw);
    float cov  = fmaf(-mx, my, swxy * inv_sw);
    float A = cov / (varx + 1e-6f);
    float b = my - A * mx;
    float bdet = sv / swd;
    out[h * W + c] = A * Xc + b + (xcen - Xc) + bdet;
}

extern "C" void kernel_launch(void* const* d_in, const int* in_sizes, int n_in,
                              void* d_out, int out_size, void* d_ws, size_t ws_size,
                              hipStream_t stream) {
    const float* X = (const float*)d_in[0];
    const float* y = (const float*)d_in[1];
    const float* r = (const float*)d_in[2];
    float* out = (float*)d_out;
    float* wsf = (float*)d_ws;

    float* inv_s2  = wsf;             // 1 float
    float* partial = wsf + 64;        // 512 floats (256 mins, 256 maxs)
    float* Xb      = wsf + 1024;      // 262144 floats
    float* yb      = Xb + NPIX;       // 262144 floats

    k_reduce<<<256, 256, 0, stream>>>(y, partial);
    k_sigma<<<1, 256, 0, stream>>>(partial, r, inv_s2);
    k_base<<<dim3(8, 128), dim3(64, 4), 0, stream>>>(X, y, Xb, yb);
    k_main<<<dim3(8, 128), dim3(64, 4), 0, stream>>>(X, y, Xb, yb, inv_s2, out);
}

// Round 2
// 109.406 us; speedup vs baseline: 1.1649x; 1.1649x over previous
//
#include <hip/hip_runtime.h>

#define W 512
#define NPIX (512*512)

// ---------------- reduction: min/max of y ----------------
__global__ __launch_bounds__(256) void k_reduce(const float* __restrict__ y,
                                                float* __restrict__ partial) {
    __shared__ float smn[256], smx[256];
    int t = threadIdx.x;
    int base = blockIdx.x * 1024 + t;
    float mn = 1e30f, mx = -1e30f;
#pragma unroll
    for (int k = 0; k < 4; ++k) {
        float v = y[base + k * 256];
        mn = fminf(mn, v);
        mx = fmaxf(mx, v);
    }
    smn[t] = mn; smx[t] = mx;
    __syncthreads();
    for (int off = 128; off > 0; off >>= 1) {
        if (t < off) {
            smn[t] = fminf(smn[t], smn[t + off]);
            smx[t] = fmaxf(smx[t], smx[t + off]);
        }
        __syncthreads();
    }
    if (t == 0) {
        partial[blockIdx.x]       = smn[0];
        partial[256 + blockIdx.x] = smx[0];
    }
}

__global__ __launch_bounds__(256) void k_sigma(const float* __restrict__ partial,
                                               const float* __restrict__ r,
                                               float* __restrict__ k2out) {
    __shared__ float smn[256], smx[256];
    int t = threadIdx.x;
    smn[t] = partial[t];
    smx[t] = partial[256 + t];
    __syncthreads();
    for (int off = 128; off > 0; off >>= 1) {
        if (t < off) {
            smn[t] = fminf(smn[t], smn[t + off]);
            smx[t] = fmaxf(smx[t], smx[t + off]);
        }
        __syncthreads();
    }
    if (t == 0) {
        float sigma = r[0] * (smx[0] - smn[0]);
        float hh = 0.5f * sigma;
        // k2 = -log2(e)/ (sigma/2)^2 ; weight = 2^(d^2 * k2)
        k2out[0] = -1.4426950408889634f / (hh * hh);
    }
}

__device__ __forceinline__ float fexp2(float x) {
#if __has_builtin(__builtin_amdgcn_exp2f)
    return __builtin_amdgcn_exp2f(x);
#else
    return __expf(x * 0.6931471805599453f);
#endif
}

// ---------------- separable 9-box: row pass (zero-padded cols) ----------------
__global__ __launch_bounds__(256) void k_row(const float* __restrict__ X,
                                             const float* __restrict__ y,
                                             float* __restrict__ tmpX,
                                             float* __restrict__ tmpY) {
    __shared__ float sX[4][80], sY[4][80];
    int tx = threadIdx.x, ty = threadIdx.y;
    int c0 = blockIdx.x * 64;
    int h  = blockIdx.y * 4 + ty;
    // stage cols c0-4 .. c0+67 (72 entries), zero-padded at image edges
    {
        int col = c0 - 4 + tx;
        sX[ty][tx] = ((unsigned)col < 512u) ? X[h * W + col] : 0.f;
        sY[ty][tx] = ((unsigned)col < 512u) ? y[h * W + col] : 0.f;
        if (tx < 8) {
            int col2 = c0 + 60 + tx;
            sX[ty][64 + tx] = ((unsigned)col2 < 512u) ? X[h * W + col2] : 0.f;
            sY[ty][64 + tx] = ((unsigned)col2 < 512u) ? y[h * W + col2] : 0.f;
        }
    }
    __syncthreads();
    float sx = 0.f, sy = 0.f;
#pragma unroll
    for (int j = 0; j < 9; ++j) {
        sx += sX[ty][tx + j];
        sy += sY[ty][tx + j];
    }
    int c = c0 + tx;
    tmpX[h * W + c] = sx;
    tmpY[h * W + c] = sy;
}

// ---------------- col pass: finish box, emit Xb, yb, Xd=X-Xb, D=(y-yb)-(X-Xb) ----------------
__global__ __launch_bounds__(256) void k_col(const float* __restrict__ X,
                                             const float* __restrict__ y,
                                             const float* __restrict__ tmpX,
                                             const float* __restrict__ tmpY,
                                             float* __restrict__ Xb,
                                             float* __restrict__ yb,
                                             float* __restrict__ Xd,
                                             float* __restrict__ Dd) {
    int c = blockIdx.x * 64 + threadIdx.x;
    int h = blockIdx.y * 4 + threadIdx.y;
    float sx = 0.f, sy = 0.f;
#pragma unroll
    for (int dy = -4; dy <= 4; ++dy) {
        int nh = h + dy;                 // wave-uniform validity
        if ((unsigned)nh < 512u) {
            sx += tmpX[nh * W + c];
            sy += tmpY[nh * W + c];
        }
    }
    const float inv81 = 1.0f / 81.0f;
    float xbv = sx * inv81, ybv = sy * inv81;
    int p = h * W + c;
    float xv = X[p], yv = y[p];
    float xd = xv - xbv;
    Xb[p] = xbv;
    yb[p] = ybv;
    Xd[p] = xd;
    Dd[p] = (yv - ybv) - xd;
}

// ---------------- main fused kernel ----------------
__global__ __launch_bounds__(256) void k_main(const float* __restrict__ Xb,
                                              const float* __restrict__ yb,
                                              const float* __restrict__ Xd,
                                              const float* __restrict__ Dd,
                                              const float* __restrict__ k2p,
                                              float* __restrict__ out) {
    __shared__ float sbx[19];   // 1D spatial for 19x19 (separable, symmetric)
    __shared__ float sdx[9];    // 1D col spatial for 5x9
    __shared__ float sdy[5];    // 1D row spatial for 5x9
    int t = threadIdx.y * 64 + threadIdx.x;
    if (t < 19) { int d = t - 9; sbx[t] = __expf(-(float)(d * d) / 8145.0625f); }
    else if (t < 32) { int u = t - 19; if (u < 9)  { int d = u - 4; sdx[u] = __expf(-(float)(d * d) / 126.5625f); } }
    else if (t < 40) { int u = t - 32; if (u < 5)  { int d = u - 2; sdy[u] = __expf(-(float)(d * d) / 126.5625f); } }
    __syncthreads();

    float k2 = k2p[0];
    int c = blockIdx.x * 64 + threadIdx.x;
    int h = blockIdx.y * 4 + threadIdx.y;

    // chunk mapping: output col -> owning chunk after overlap-trim
    int chunk = (c == 0) ? 0 : (c - 1) / 62;
    if (chunk > 8) chunk = 8;
    int s = 62 * chunk;
    int e = (chunk == 8) ? 512 : (s + 64);

    // per-lane column weights, chunk validity folded in (zero outside [s,e))
    float colw[19];
#pragma unroll
    for (int j = 0; j < 19; ++j) {
        int nc = c - 9 + j;
        colw[j] = ((nc >= s) & (nc < e)) ? sbx[j] : 0.f;
    }
    float colwd[9];
#pragma unroll
    for (int j = 0; j < 9; ++j) {
        int nc = c - 4 + j;
        colwd[j] = ((nc >= s) & (nc < e)) ? sdx[j] : 0.f;
    }

    int p = h * W + c;
    float Xc  = Xb[p];
    float Xdc = Xd[p];

    // ---- base pass: 19x19 bilateral guided-filter stats ----
    float sw = 0.f, swy = 0.f, swx = 0.f, swxx = 0.f, swxy = 0.f;
#pragma unroll 1
    for (int dy = -9; dy <= 9; ++dy) {
        int nh = h + dy;                       // wave-uniform
        if ((unsigned)nh >= 512u) continue;
        const float* xr = Xb + nh * W + c;
        const float* yr = yb + nh * W + c;
        float ey = sbx[dy + 9];
        float rs = 0.f, rsx = 0.f, rsy = 0.f, rsxx = 0.f, rsxy = 0.f;
#pragma unroll
        for (int j = 0; j < 19; ++j) {
            float xv = xr[j - 9];
            float yv = yr[j - 9];
            float dd = xv - Xc;
            float w  = fexp2(dd * (dd * k2)) * colw[j];
            float tt = w * xv;
            rs   += w;
            rsx  += tt;
            rsy  = fmaf(w, yv, rsy);
            rsxx = fmaf(tt, xv, rsxx);
            rsxy = fmaf(tt, yv, rsxy);
        }
        sw   = fmaf(ey, rs,   sw);
        swx  = fmaf(ey, rsx,  swx);
        swy  = fmaf(ey, rsy,  swy);
        swxx = fmaf(ey, rsxx, swxx);
        swxy = fmaf(ey, rsxy, swxy);
    }

    // ---- detail pass: 5(h)x9(w) bilateral on residuals ----
    float swd = 0.f, sv = 0.f;
#pragma unroll 1
    for (int dy = -2; dy <= 2; ++dy) {
        int nh = h + dy;                       // wave-uniform
        if ((unsigned)nh >= 512u) continue;
        const float* xr = Xd + nh * W + c;
        const float* dr = Dd + nh * W + c;
        float ey = sdy[dy + 2];
        float rs = 0.f, rv = 0.f;
#pragma unroll
        for (int j = 0; j < 9; ++j) {
            float xd = xr[j - 4];
            float dv = dr[j - 4];
            float dd = xd - Xdc;
            float w  = fexp2(dd * (dd * k2)) * colwd[j];
            rs += w;
            rv  = fmaf(w, dv, rv);
        }
        swd = fmaf(ey, rs, swd);
        sv  = fmaf(ey, rv, sv);
    }

    // ---- combine ----
    float inv_sw = 1.0f / sw;
    float mx = swx * inv_sw, my = swy * inv_sw;
    float varx = fmaf(-mx, mx, swxx * inv_sw);
    float cov  = fmaf(-mx, my, swxy * inv_sw);
    float A = cov / (varx + 1e-6f);
    float b = my - A * mx;
    out[p] = A * Xc + b + Xdc + sv / swd;
}

extern "C" void kernel_launch(void* const* d_in, const int* in_sizes, int n_in,
                              void* d_out, int out_size, void* d_ws, size_t ws_size,
                              hipStream_t stream) {
    const float* X = (const float*)d_in[0];
    const float* y = (const float*)d_in[1];
    const float* r = (const float*)d_in[2];
    float* out = (float*)d_out;
    float* wsf = (float*)d_ws;

    const int GA = 256;                    // guard floats around each array
    float* k2      = wsf;                  // 1 float
    float* partial = wsf + 64;             // 512 floats
    float* tmpX = wsf + 1024 + GA;
    float* tmpY = tmpX + NPIX + 2 * GA;
    float* Xb   = tmpY + NPIX + 2 * GA;
    float* yb   = Xb   + NPIX + 2 * GA;
    float* Xd   = yb   + NPIX + 2 * GA;
    float* Dd   = Xd   + NPIX + 2 * GA;

    k_reduce<<<256, 256, 0, stream>>>(y, partial);
    k_sigma<<<1, 256, 0, stream>>>(partial, r, k2);
    k_row<<<dim3(8, 128), dim3(64, 4), 0, stream>>>(X, y, tmpX, tmpY);
    k_col<<<dim3(8, 128), dim3(64, 4), 0, stream>>>(X, y, tmpX, tmpY, Xb, yb, Xd, Dd);
    k_main<<<dim3(8, 128), dim3(64, 4), 0, stream>>>(Xb, yb, Xd, Dd, k2, out);
}

// Round 3
// 103.044 us; speedup vs baseline: 1.2368x; 1.0617x over previous
//
#include <hip/hip_runtime.h>

#define W 512
#define NPIX (512*512)

// ---------------- reduction: min/max of y (512 partials) ----------------
__global__ __launch_bounds__(256) void k_reduce(const float* __restrict__ y,
                                                float* __restrict__ partial) {
    __shared__ float smn[256], smx[256];
    int t = threadIdx.x;
    int base = blockIdx.x * 1024 + t;
    float mn = 1e30f, mx = -1e30f;
#pragma unroll
    for (int k = 0; k < 4; ++k) {
        float v = y[base + k * 256];
        mn = fminf(mn, v);
        mx = fmaxf(mx, v);
    }
    smn[t] = mn; smx[t] = mx;
    __syncthreads();
    for (int off = 128; off > 0; off >>= 1) {
        if (t < off) {
            smn[t] = fminf(smn[t], smn[t + off]);
            smx[t] = fmaxf(smx[t], smx[t + off]);
        }
        __syncthreads();
    }
    if (t == 0) {
        partial[blockIdx.x]       = smn[0];
        partial[256 + blockIdx.x] = smx[0];
    }
}

__device__ __forceinline__ float fexp2(float x) {
#if __has_builtin(__builtin_amdgcn_exp2f)
    return __builtin_amdgcn_exp2f(x);
#else
    return __expf(x * 0.6931471805599453f);
#endif
}

// ---------------- fused box prep: 9x9 box via LDS separable, emits interleaved
// XYb = (Xb, yb) and XDd = (Xd, D=(y-yb)-Xd). Extra grid row (blockIdx.y==64)
// does the sigma partial-combine. ----------------
__global__ __launch_bounds__(512) void k_prep(const float* __restrict__ X,
                                              const float* __restrict__ y,
                                              const float* __restrict__ partial,
                                              const float* __restrict__ r,
                                              float2* __restrict__ XYb,
                                              float2* __restrict__ XDd,
                                              float* __restrict__ k2out) {
    int tx = threadIdx.x, ty = threadIdx.y;
    int t = ty * 64 + tx;
    if (blockIdx.y == 64) {                    // sigma block
        if (blockIdx.x != 0) return;
        __shared__ float smn[256], smx[256];
        if (t < 256) { smn[t] = partial[t]; smx[t] = partial[256 + t]; }
        __syncthreads();
        for (int off = 128; off > 0; off >>= 1) {
            if (t < off) { smn[t] = fminf(smn[t], smn[t + off]); smx[t] = fmaxf(smx[t], smx[t + off]); }
            __syncthreads();
        }
        if (t == 0) {
            float sigma = r[0] * (smx[0] - smn[0]);
            float hh = 0.5f * sigma;
            k2out[0] = -1.4426950408889634f / (hh * hh);   // weight = 2^(d^2*k2)
        }
        return;
    }
    __shared__ float sX[16][72], sY[16][72];
    __shared__ float rX[16][64], rY[16][64];
    int c0 = blockIdx.x * 64, r0 = blockIdx.y * 8;
    for (int i = t; i < 16 * 72; i += 512) {
        int rr = i / 72, cc = i - rr * 72;
        int gr = r0 - 4 + rr, gc = c0 - 4 + cc;
        bool ok = ((unsigned)gr < 512u) & ((unsigned)gc < 512u);
        sX[rr][cc] = ok ? X[gr * W + gc] : 0.f;
        sY[rr][cc] = ok ? y[gr * W + gc] : 0.f;
    }
    __syncthreads();
    for (int i = t; i < 16 * 64; i += 512) {
        int rr = i >> 6, cc = i & 63;
        float ax = 0.f, ay = 0.f;
#pragma unroll
        for (int j = 0; j < 9; ++j) { ax += sX[rr][cc + j]; ay += sY[rr][cc + j]; }
        rX[rr][cc] = ax; rY[rr][cc] = ay;
    }
    __syncthreads();
    float ax = 0.f, ay = 0.f;
#pragma unroll
    for (int j = 0; j < 9; ++j) { ax += rX[ty + j][tx]; ay += rY[ty + j][tx]; }
    const float inv81 = 1.0f / 81.0f;
    float xb = ax * inv81, yb = ay * inv81;
    float xv = sX[ty + 4][tx + 4], yv = sY[ty + 4][tx + 4];
    float xd = xv - xb;
    int p = (r0 + ty) * W + (c0 + tx);
    XYb[p] = make_float2(xb, yb);
    XDd[p] = make_float2(xd, (yv - yb) - xd);
}

// ---------------- main fused kernel: 2 vertical pixels per thread ----------------
__global__ __launch_bounds__(128) void k_main(const float2* __restrict__ XYb,
                                              const float2* __restrict__ XDd,
                                              const float* __restrict__ k2p,
                                              float* __restrict__ out) {
    __shared__ float sbx[19];   // 1D spatial for 19x19 (separable)
    __shared__ float sdx[9];    // 1D col spatial for 5x9
    __shared__ float sdy[5];    // 1D row spatial for 5x9
    int tx = threadIdx.x, ty = threadIdx.y;
    int t = ty * 64 + tx;
    if (t < 19)      { int d = t - 9;      sbx[t]      = __expf(-(float)(d * d) / 8145.0625f); }
    else if (t < 28) { int d = t - 19 - 4; sdx[t - 19] = __expf(-(float)(d * d) / 126.5625f); }
    else if (t < 33) { int d = t - 28 - 2; sdy[t - 28] = __expf(-(float)(d * d) / 126.5625f); }
    __syncthreads();

    float k2 = k2p[0];
    int c  = blockIdx.x * 64 + tx;
    int h0 = (blockIdx.y * 2 + ty) * 2;     // this thread: rows h0, h0+1

    // chunk mapping: output col -> owning chunk after overlap-trim
    int chunk = (c == 0) ? 0 : (c - 1) / 62;
    if (chunk > 8) chunk = 8;
    int s = 62 * chunk;
    int e = (chunk == 8) ? 512 : (s + 64);

    float colw[19];
#pragma unroll
    for (int j = 0; j < 19; ++j) {
        int nc = c - 9 + j;
        colw[j] = ((nc >= s) & (nc < e)) ? sbx[j] : 0.f;
    }
    float colwd[9];
#pragma unroll
    for (int j = 0; j < 9; ++j) {
        int nc = c - 4 + j;
        colwd[j] = ((nc >= s) & (nc < e)) ? sdx[j] : 0.f;
    }

    int p0 = h0 * W + c;
    float Xc0  = XYb[p0].x,     Xc1  = XYb[p0 + W].x;
    float2 cd0 = XDd[p0];
    float2 cd1 = XDd[p0 + W];
    float Xd0 = cd0.x, Xd1 = cd1.x;

    // ---- base pass: 19x19 bilateral guided-filter stats, 2 px ----
    float sw0 = 0.f, swx0 = 0.f, swy0 = 0.f, swxx0 = 0.f, swxy0 = 0.f;
    float sw1 = 0.f, swx1 = 0.f, swy1 = 0.f, swxx1 = 0.f, swxy1 = 0.f;
#pragma unroll 1
    for (int nh = h0 - 9; nh <= h0 + 10; ++nh) {
        if ((unsigned)nh >= 512u) continue;          // wave-uniform
        int dy0 = nh - h0;                            // -9..10 (px1: dy0-1)
        const float2* xr = XYb + (nh * W + c);
        float rs0 = 0.f, rsx0 = 0.f, rsy0 = 0.f, rsxx0 = 0.f, rsxy0 = 0.f;
        float rs1 = 0.f, rsx1 = 0.f, rsy1 = 0.f, rsxx1 = 0.f, rsxy1 = 0.f;
#pragma unroll
        for (int j = 0; j < 19; ++j) {
            float2 v = xr[j - 9];
            float xv = v.x, yv = v.y;
            float u0 = xv - Xc0,        u1 = xv - Xc1;
            float a0 = u0 * (u0 * k2),  a1 = u1 * (u1 * k2);
            float w0 = fexp2(a0) * colw[j];
            float w1 = fexp2(a1) * colw[j];
            rs0 += w0;                      rs1 += w1;
            rsx0 = fmaf(w0, xv, rsx0);      rsx1 = fmaf(w1, xv, rsx1);
            rsy0 = fmaf(w0, yv, rsy0);      rsy1 = fmaf(w1, yv, rsy1);
            float t0 = w0 * xv,             t1 = w1 * xv;
            rsxx0 = fmaf(t0, xv, rsxx0);    rsxx1 = fmaf(t1, xv, rsxx1);
            rsxy0 = fmaf(t0, yv, rsxy0);    rsxy1 = fmaf(t1, yv, rsxy1);
        }
        float ey0 = (dy0 <= 9)  ? sbx[dy0 + 9] : 0.f;
        float ey1 = (dy0 >= -8) ? sbx[dy0 + 8] : 0.f;
        sw0   = fmaf(ey0, rs0,   sw0);    sw1   = fmaf(ey1, rs1,   sw1);
        swx0  = fmaf(ey0, rsx0,  swx0);   swx1  = fmaf(ey1, rsx1,  swx1);
        swy0  = fmaf(ey0, rsy0,  swy0);   swy1  = fmaf(ey1, rsy1,  swy1);
        swxx0 = fmaf(ey0, rsxx0, swxx0);  swxx1 = fmaf(ey1, rsxx1, swxx1);
        swxy0 = fmaf(ey0, rsxy0, swxy0);  swxy1 = fmaf(ey1, rsxy1, swxy1);
    }

    // ---- detail pass: 5(h)x9(w) bilateral on residuals, 2 px ----
    float swd0 = 0.f, sv0 = 0.f, swd1 = 0.f, sv1 = 0.f;
#pragma unroll 1
    for (int nh = h0 - 2; nh <= h0 + 3; ++nh) {
        if ((unsigned)nh >= 512u) continue;
        int dyd = nh - h0;                            // -2..3
        const float2* dr = XDd + (nh * W + c);
        float rs0 = 0.f, rv0 = 0.f, rs1 = 0.f, rv1 = 0.f;
#pragma unroll
        for (int j = 0; j < 9; ++j) {
            float2 v = dr[j - 4];
            float xd = v.x, dv = v.y;
            float u0 = xd - Xd0,        u1 = xd - Xd1;
            float a0 = u0 * (u0 * k2),  a1 = u1 * (u1 * k2);
            float w0 = fexp2(a0) * colwd[j];
            float w1 = fexp2(a1) * colwd[j];
            rs0 += w0;                  rs1 += w1;
            rv0 = fmaf(w0, dv, rv0);    rv1 = fmaf(w1, dv, rv1);
        }
        float ey0 = (dyd <= 2)  ? sdy[dyd + 2] : 0.f;
        float ey1 = (dyd >= -1) ? sdy[dyd + 1] : 0.f;
        swd0 = fmaf(ey0, rs0, swd0);  swd1 = fmaf(ey1, rs1, swd1);
        sv0  = fmaf(ey0, rv0, sv0);   sv1  = fmaf(ey1, rv1, sv1);
    }

    // ---- combine & store both pixels ----
    {
        float inv = 1.0f / sw0;
        float mx = swx0 * inv, my = swy0 * inv;
        float varx = fmaf(-mx, mx, swxx0 * inv);
        float cov  = fmaf(-mx, my, swxy0 * inv);
        float A = cov / (varx + 1e-6f);
        float b = my - A * mx;
        out[p0] = A * Xc0 + b + Xd0 + sv0 / swd0;
    }
    {
        float inv = 1.0f / sw1;
        float mx = swx1 * inv, my = swy1 * inv;
        float varx = fmaf(-mx, mx, swxx1 * inv);
        float cov  = fmaf(-mx, my, swxy1 * inv);
        float A = cov / (varx + 1e-6f);
        float b = my - A * mx;
        out[p0 + W] = A * Xc1 + b + Xd1 + sv1 / swd1;
    }
}

extern "C" void kernel_launch(void* const* d_in, const int* in_sizes, int n_in,
                              void* d_out, int out_size, void* d_ws, size_t ws_size,
                              hipStream_t stream) {
    const float* X = (const float*)d_in[0];
    const float* y = (const float*)d_in[1];
    const float* r = (const float*)d_in[2];
    float* out = (float*)d_out;
    float* wsf = (float*)d_ws;

    float* k2      = wsf;                                  // 1 float
    float* partial = wsf + 64;                             // 512 floats
    float2* XYb = (float2*)(wsf + 1024) + 256;             // guarded
    float2* XDd = XYb + NPIX + 512;                        // guarded

    k_reduce<<<256, 256, 0, stream>>>(y, partial);
    k_prep<<<dim3(8, 65), dim3(64, 8), 0, stream>>>(X, y, partial, r, XYb, XDd, k2);
    k_main<<<dim3(8, 128), dim3(64, 2), 0, stream>>>(XYb, XDd, k2, out);
}